// Round 28
// baseline (232.776 us; speedup 1.0000x reference)
//
#include <hip/hip_runtime.h>

#define EPSF 1e-7f
#define NBMAX 512   // max dst-buckets (ceil(N/128)); N=50000 -> 391

typedef __attribute__((ext_vector_type(4))) _Float16 half4;
typedef __attribute__((ext_vector_type(8))) _Float16 half8;
typedef __attribute__((ext_vector_type(2))) _Float16 half2v;
typedef __attribute__((ext_vector_type(4))) float f32x4;
typedef unsigned long long u64;

__device__ __forceinline__ float lrelu02(float x){ return x > 0.f ? x : 0.2f*x; }

// ------- merged precompute: w1t, w2t, partial dst-histograms, lx = logmap0(x) -------
//   blocks 0..127: w1t | 128..191: w2t | 192..703: 2x256 partial hists | 704+: lx
__global__ __launch_bounds__(256) void k_pre(
    const float* __restrict__ W1, const float* __restrict__ W2,
    const float* __restrict__ x,
    const int* __restrict__ dst0, int E0, const int* __restrict__ dst1, int E1,
    _Float16* __restrict__ w1t, _Float16* __restrict__ w2t,
    int* __restrict__ part0, int* __restrict__ part1,
    _Float16* __restrict__ lxh, int N) {
  const int b = blockIdx.x, tid = threadIdx.x;
  if (b < 128) {                       // w1t [256][128] = W1^T fp16
    int idx = b*256 + tid;
    int j = idx >> 7, k = idx & 127;
    w1t[idx] = (_Float16)W1[(size_t)k*256 + j];
    return;
  }
  if (b < 192) {                       // w2t [64][256] = W2^T fp16
    int idx = (b-128)*256 + tid;
    int j = idx >> 8, k = idx & 255;
    w2t[idx] = (_Float16)W2[(size_t)k*64 + j];
    return;
  }
  if (b < 704) {                       // partial histograms (256 blocks per graph)
    const int pb = b - 192;
    const int g = pb >> 8, p = pb & 255;
    const int* dst = g ? dst1 : dst0;
    const int E = g ? E1 : E0;
    int* part = g ? part1 : part0;
    __shared__ int hist[NBMAX];
    for (int i = tid; i < NBMAX; i += 256) hist[i] = 0;
    __syncthreads();
    const int per = (E + 255) >> 8;
    const int lo = p * per, hi = min(lo + per, E);
    for (int i = lo + tid; i < hi; i += 256)
      atomicAdd(&hist[dst[i] >> 7], 1);
    __syncthreads();
    for (int i = tid; i < NBMAX; i += 256) part[p*NBMAX + i] = hist[i];
    return;
  }
  // lx = logmap0(x) fp16: wave per row
  int tidg = (b - 704)*256 + tid;
  int wid = tidg >> 6, lane = tidg & 63;
  int nw = (gridDim.x - 704) * 4;
  for (int row = wid; row < N; row += nw) {
    float2 v = *(const float2*)(x + (size_t)row*128 + lane*2);
    float ss = v.x*v.x + v.y*v.y;
    #pragma unroll
    for (int o = 32; o; o >>= 1) ss += __shfl_xor(ss, o);
    float n  = fmaxf(sqrtf(ss), EPSF);
    float nc = fminf(n, 1.f - 1e-5f);
    float sc = atanhf(nc) / n;                 // logmap0 scale
    half2v hv; hv.x = (_Float16)(v.x*sc); hv.y = (_Float16)(v.y*sc);
    *(half2v*)(lxh + (size_t)row*128 + lane*2) = hv;
  }
}

__global__ __launch_bounds__(256) void k_bucketA(
    const int* __restrict__ src0, const int* __restrict__ dst0,
    int* __restrict__ bcur0, u64* __restrict__ temp0, int E0, int blocksA0,
    const int* __restrict__ src1, const int* __restrict__ dst1,
    int* __restrict__ bcur1, u64* __restrict__ temp1, int E1, int nb) {
  const int g0 = (blockIdx.x < blocksA0);
  const int* src = g0 ? src0 : src1;
  const int* dst = g0 ? dst0 : dst1;
  int* bcur      = g0 ? bcur0 : bcur1;
  u64* temp      = g0 ? temp0 : temp1;
  const int E    = g0 ? E0 : E1;
  const int cb   = g0 ? blockIdx.x : blockIdx.x - blocksA0;
  __shared__ int hist[NBMAX];
  __shared__ int lbase[NBMAX];
  const int tid = threadIdx.x;
  const int chunk0 = cb * 4096;
  const int e_end = min(chunk0 + 4096, E);
  for (int i = tid; i < nb; i += 256) hist[i] = 0;
  __syncthreads();
  for (int i = chunk0 + tid; i < e_end; i += 256)
    atomicAdd(&hist[dst[i] >> 7], 1);
  __syncthreads();
  for (int bn = tid; bn < nb; bn += 256) {
    int c = hist[bn];
    lbase[bn] = c ? atomicAdd(&bcur[bn], c) : 0;
    hist[bn] = 0;
  }
  __syncthreads();
  for (int i = chunk0 + tid; i < e_end; i += 256) {
    int d = dst[i];
    int bn = d >> 7;
    int off = atomicAdd(&hist[bn], 1);
    temp[(size_t)lbase[bn] + off] = ((u64)(unsigned)d << 32) | (unsigned)src[i];
  }
}

// pass B: per bucket, per-dst count + local scan -> rowptr; scatter csrc.
// graph 0: also per-edge attention weights (fp16). graph 1: also cdst (for k_w1e).
__global__ __launch_bounds__(256) void k_bucketB2(
    const u64* __restrict__ temp0, const int* __restrict__ bbase0,
    int* __restrict__ rowptr0, int* __restrict__ csrc0,
    const float* __restrict__ es1, const float* __restrict__ ed1,
    half4* __restrict__ w0,
    const u64* __restrict__ temp1, const int* __restrict__ bbase1,
    int* __restrict__ rowptr1, int* __restrict__ csrc1,
    int* __restrict__ cdst1, int N, int nb) {
  const int g0 = (blockIdx.x < nb);
  const u64* temp = g0 ? temp0 : temp1;
  const int* bbase = g0 ? bbase0 : bbase1;
  int* rowptr = g0 ? rowptr0 : rowptr1;
  int* csrc   = g0 ? csrc0 : csrc1;
  const int b = g0 ? blockIdx.x : blockIdx.x - nb;
  __shared__ int lcnt[128];
  __shared__ int lcur[128];
  __shared__ int wt4[4];
  __shared__ float ledv[512];
  const int tid = threadIdx.x;
  const int d0 = b << 7;
  const int d1 = min(d0 + 128, N);
  const int lo = bbase[b], hi = bbase[b+1];
  if (tid < 128) lcnt[tid] = 0;
  if (g0) {
    for (int i = tid; i < (d1 - d0)*4; i += 256) ledv[i] = ed1[d0*4 + i];
  }
  __syncthreads();
  for (int k = lo + tid; k < hi; k += 256)
    atomicAdd(&lcnt[(int)(temp[k] >> 32) - d0], 1);
  __syncthreads();
  int v = (tid < 128) ? lcnt[tid] : 0;
  const int lane = tid & 63, w = tid >> 6;
  int inc = v;
  #pragma unroll
  for (int o = 1; o < 64; o <<= 1) { int t = __shfl_up(inc, o); if (lane >= o) inc += t; }
  if (lane == 63) wt4[w] = inc;
  __syncthreads();
  int woff = 0;
  for (int i = 0; i < w; ++i) woff += wt4[i];
  int excl = lo + woff + inc - v;
  if (tid < d1 - d0) { rowptr[d0 + tid] = excl; lcur[tid] = excl; }
  if (b == nb-1 && tid == 0) rowptr[N] = hi;
  __syncthreads();
  for (int k = lo + tid; k < hi; k += 256) {
    u64 p = temp[k];
    int d = (int)(p >> 32);
    int s = (int)(unsigned)p;
    int pos = atomicAdd(&lcur[d - d0], 1);
    csrc[pos] = s;
    if (g0) {
      float4 e = *(const float4*)(es1 + (size_t)s*4);
      int ld = (d - d0)*4;
      half4 wh;
      wh.x = (_Float16)__expf(lrelu02(e.x + ledv[ld+0]));
      wh.y = (_Float16)__expf(lrelu02(e.y + ledv[ld+1]));
      wh.z = (_Float16)__expf(lrelu02(e.z + ledv[ld+2]));
      wh.w = (_Float16)__expf(lrelu02(e.w + ledv[ld+3]));
      w0[pos] = wh;
    } else {
      cdst1[pos] = d;
    }
  }
}

// ------------- gemm1 via MFMA: h1 = lx @ W1 (fp16 in, f32 acc, fp16 out)
//   + epilogue: es1/ed1 [N,4] from the h1 LDS tile
//   + 2 appended blocks: bucket-count scan (sums k_pre partials) -> bbase/bcur
#define LXP 136   // padded halves per lx row in LDS
#define H1P 264   // padded halves per h1 row in LDS
__global__ __launch_bounds__(256) void k_gemm1_mfma(
    const _Float16* __restrict__ lxh, const _Float16* __restrict__ w1t,
    const float* __restrict__ a_src, const float* __restrict__ a_dst,
    _Float16* __restrict__ h1h, float* __restrict__ es, float* __restrict__ ed,
    const int* __restrict__ part0, const int* __restrict__ part1,
    int* __restrict__ bbase0, int* __restrict__ bcur0,
    int* __restrict__ bbase1, int* __restrict__ bcur1, int nb, int N) {
  __shared__ _Float16 lxs[32*LXP];   // ~8.5 KB
  __shared__ _Float16 h1s[32*H1P];   // ~16.5 KB
  __shared__ int swt[4];
  const int tid = threadIdx.x;
  const int nblk = (N + 31) >> 5;
  if ((int)blockIdx.x >= nblk) {
    // ---- bucket scan for graph g (replaces k_bscan) ----
    const int g = (int)blockIdx.x - nblk;
    const int* part = g ? part1 : part0;
    int* bbase = g ? bbase1 : bbase0;
    int* bcur  = g ? bcur1  : bcur0;
    const int i0 = tid*2, i1 = tid*2 + 1;
    int v0 = 0, v1 = 0;
    for (int p = 0; p < 256; ++p) {
      v0 += part[p*NBMAX + i0];
      v1 += part[p*NBMAX + i1];
    }
    int s = v0 + v1;
    const int lane = tid & 63, w = tid >> 6;
    int inc = s;
    #pragma unroll
    for (int o = 1; o < 64; o <<= 1) { int t = __shfl_up(inc, o); if (lane >= o) inc += t; }
    if (lane == 63) swt[w] = inc;
    __syncthreads();
    int woff = 0;
    for (int i = 0; i < w; ++i) woff += swt[i];
    int excl = woff + inc - s;
    if (i0 < nb) { bbase[i0] = excl; bcur[i0] = excl; }
    if (i1 < nb) { bbase[i1] = excl + v0; bcur[i1] = excl + v0; }
    if (tid == 255) bbase[nb] = excl + s;   // beyond-nb partials are zero
    return;
  }
  const int block0 = blockIdx.x * 32;
  const int vrows = min(32, N - block0);
  for (int i = tid; i < 512; i += 256) {
    int r = i >> 4, c = (i & 15) * 8;
    uint4 v = make_uint4(0u,0u,0u,0u);
    if (r < vrows) v = *(const uint4*)(lxh + (size_t)(block0 + r)*128 + c);
    *(uint4*)(lxs + r*LXP + c) = v;
  }
  __syncthreads();
  const int wv = tid >> 6, lane = tid & 63;
  const int rt = wv & 1;               // row-tile (16 rows)
  const int ch = wv >> 1;              // col-half (128 cols)
  const int arow = rt*16 + (lane & 15);
  const int koff = (lane >> 4) * 8;
  f32x4 acc[8];
  #pragma unroll
  for (int t = 0; t < 8; ++t) acc[t] = (f32x4){0.f,0.f,0.f,0.f};
  #pragma unroll
  for (int ks = 0; ks < 4; ++ks) {
    half8 a = *(const half8*)(lxs + arow*LXP + ks*32 + koff);
    #pragma unroll
    for (int t = 0; t < 8; ++t) {
      const int col0 = ch*128 + t*16;
      half8 b = *(const half8*)(w1t + (size_t)(col0 + (lane & 15))*128 + ks*32 + koff);
      acc[t] = __builtin_amdgcn_mfma_f32_16x16x32_f16(a, b, acc[t], 0, 0, 0);
    }
  }
  #pragma unroll
  for (int t = 0; t < 8; ++t) {
    const int col = ch*128 + t*16 + (lane & 15);
    #pragma unroll
    for (int r = 0; r < 4; ++r) {
      const int row = rt*16 + (lane >> 4)*4 + r;
      h1s[row*H1P + col] = (_Float16)acc[t][r];
    }
  }
  __syncthreads();
  for (int i = tid; i < 1024; i += 256) {
    int r = i >> 5, c = (i & 31) * 8;
    if (r < vrows) {
      uint4 v = *(const uint4*)(h1s + r*H1P + c);
      *(uint4*)(h1h + (size_t)(block0 + r)*256 + c) = v;
    }
  }
  // epilogue: es/ed per (row, head) from h1s; lane owns cols lane*4..+3
  const int head = lane >> 4;
  const float4 as4 = *(const float4*)(a_src + lane*4);
  const float4 ad4 = *(const float4*)(a_dst + lane*4);
  #pragma unroll
  for (int r8 = 0; r8 < 8; ++r8) {
    int rl = wv*8 + r8;
    int row = block0 + rl;
    if (row >= N) break;
    half4 hv = *(const half4*)(h1s + rl*H1P + lane*4);
    float ax = (float)hv.x, ay = (float)hv.y, az = (float)hv.z, aw = (float)hv.w;
    float ps = ax*as4.x + ay*as4.y + az*as4.z + aw*as4.w;
    float pd = ax*ad4.x + ay*ad4.y + az*ad4.z + aw*ad4.w;
    #pragma unroll
    for (int o = 8; o; o >>= 1) { ps += __shfl_xor(ps, o); pd += __shfl_xor(pd, o); }
    if ((lane & 15) == 0) { es[row*4 + head] = ps; ed[row*4 + head] = pd; }
  }
}

// ------------- layer1 aggregation: pipelined gather + packed fdot2 accumulation -----------
__global__ void k_agg1_csr(const int* __restrict__ rowptr, const int* __restrict__ csrc,
                           const half4* __restrict__ w0,
                           const _Float16* __restrict__ h1h, _Float16* __restrict__ t2h,
                           int N) {
  int tidg = blockIdx.x*blockDim.x + threadIdx.x;
  int wid = tidg >> 6, lane = tidg & 63;
  int nw = (gridDim.x * blockDim.x) >> 6;
  const int h = lane >> 4;
  const _Float16* wp = (const _Float16*)w0;
  half2v ones; ones.x = (_Float16)1.f; ones.y = (_Float16)1.f;
  for (int d = wid; d < N; d += nw) {
    const int beg = rowptr[d], end = rowptr[d+1];
    float4 acc = make_float4(0.f,0.f,0.f,0.f);
    float wsum = 0.f;
    int k = beg;
    const int kend4 = beg + ((end - beg) & ~3);
    if (k < kend4) {
      int s0 = csrc[k], s1 = csrc[k+1], s2 = csrc[k+2], s3 = csrc[k+3];
      half2v wab, wcd;
      wab.x = wp[(size_t)(k+0)*4 + h]; wab.y = wp[(size_t)(k+1)*4 + h];
      wcd.x = wp[(size_t)(k+2)*4 + h]; wcd.y = wp[(size_t)(k+3)*4 + h];
      for (;;) {
        half4 v0 = *(const half4*)(h1h + (size_t)s0*256 + lane*4);
        half4 v1 = *(const half4*)(h1h + (size_t)s1*256 + lane*4);
        half4 v2 = *(const half4*)(h1h + (size_t)s2*256 + lane*4);
        half4 v3 = *(const half4*)(h1h + (size_t)s3*256 + lane*4);
        k += 4;
        const bool more = (k < kend4);
        int t0 = 0, t1 = 0, t2 = 0, t3 = 0;
        half2v uab, ucd;
        uab.x = uab.y = ucd.x = ucd.y = (_Float16)0.f;
        if (more) {
          t0 = csrc[k]; t1 = csrc[k+1]; t2 = csrc[k+2]; t3 = csrc[k+3];
          uab.x = wp[(size_t)(k+0)*4 + h]; uab.y = wp[(size_t)(k+1)*4 + h];
          ucd.x = wp[(size_t)(k+2)*4 + h]; ucd.y = wp[(size_t)(k+3)*4 + h];
        }
        wsum = __builtin_amdgcn_fdot2(wab, ones, wsum, false);
        wsum = __builtin_amdgcn_fdot2(wcd, ones, wsum, false);
        half2v p;
        p.x = v0.x; p.y = v1.x;
        acc.x = __builtin_amdgcn_fdot2(p, wab, acc.x, false);
        p.x = v2.x; p.y = v3.x;
        acc.x = __builtin_amdgcn_fdot2(p, wcd, acc.x, false);
        p.x = v0.y; p.y = v1.y;
        acc.y = __builtin_amdgcn_fdot2(p, wab, acc.y, false);
        p.x = v2.y; p.y = v3.y;
        acc.y = __builtin_amdgcn_fdot2(p, wcd, acc.y, false);
        p.x = v0.z; p.y = v1.z;
        acc.z = __builtin_amdgcn_fdot2(p, wab, acc.z, false);
        p.x = v2.z; p.y = v3.z;
        acc.z = __builtin_amdgcn_fdot2(p, wcd, acc.z, false);
        p.x = v0.w; p.y = v1.w;
        acc.w = __builtin_amdgcn_fdot2(p, wab, acc.w, false);
        p.x = v2.w; p.y = v3.w;
        acc.w = __builtin_amdgcn_fdot2(p, wcd, acc.w, false);
        if (!more) break;
        s0 = t0; s1 = t1; s2 = t2; s3 = t3;
        wab = uab; wcd = ucd;
      }
    }
    for (; k < end; ++k) {
      int s = csrc[k];
      float wa = (float)wp[(size_t)k*4 + h];
      half4 hv = *(const half4*)(h1h + (size_t)s*256 + lane*4);
      wsum += wa;
      acc.x += wa*(float)hv.x; acc.y += wa*(float)hv.y;
      acc.z += wa*(float)hv.z; acc.w += wa*(float)hv.w;
    }
    float inv = 1.f / (wsum + 1e-16f);
    float ax = acc.x*inv, ay = acc.y*inv, az = acc.z*inv, aw = acc.w*inv;
    float ss = ax*ax + ay*ay + az*az + aw*aw;
    #pragma unroll
    for (int o = 32; o; o >>= 1) ss += __shfl_xor(ss, o);
    float n  = fmaxf(sqrtf(ss), EPSF);
    float s1 = tanhf(n) / n;                    // expmap0 scale
    float n2 = fmaxf(s1 * n, EPSF);             // = tanh(n), clamped
    float nc = fminf(n2, 1.f - 1e-5f);
    float sc = s1 * atanhf(nc) / n2;
    half4 o4; o4.x = (_Float16)(ax*sc); o4.y = (_Float16)(ay*sc);
              o4.z = (_Float16)(az*sc); o4.w = (_Float16)(aw*sc);
    *(half4*)(t2h + (size_t)d*256 + lane*4) = o4;
  }
}

// ------------- gemm2 via MFMA: h2 = t2 @ W2 (fp16 in, f32 acc); es2/ed2 epilogue
#define T2SP 264  // padded halves per t2 row in LDS
#define H2SP 72   // padded halves per h2 row in LDS
__global__ __launch_bounds__(256) void k_gemm2_mfma(
    const _Float16* __restrict__ t2h, const _Float16* __restrict__ w2t,
    const float* __restrict__ a_src, const float* __restrict__ a_dst,
    _Float16* __restrict__ h2h, float* __restrict__ es, float* __restrict__ ed, int N) {
  __shared__ _Float16 t2s[32*T2SP];  // ~16.9 KB
  __shared__ _Float16 h2s[32*H2SP];  // ~4.6 KB
  const int tid = threadIdx.x;
  const int block0 = blockIdx.x * 32;
  const int vrows = min(32, N - block0);
  for (int i = tid; i < 1024; i += 256) {
    int r = i >> 5, c = (i & 31) * 8;
    uint4 v = make_uint4(0u,0u,0u,0u);
    if (r < vrows) v = *(const uint4*)(t2h + (size_t)(block0 + r)*256 + c);
    *(uint4*)(t2s + r*T2SP + c) = v;
  }
  __syncthreads();
  const int wv = tid >> 6, lane = tid & 63;
  const int rt = wv & 1;
  const int ch = wv >> 1;
  const int arow = rt*16 + (lane & 15);
  const int koff = (lane >> 4) * 8;
  f32x4 acc[2];
  acc[0] = (f32x4){0.f,0.f,0.f,0.f};
  acc[1] = (f32x4){0.f,0.f,0.f,0.f};
  #pragma unroll
  for (int ks = 0; ks < 8; ++ks) {
    half8 a = *(const half8*)(t2s + arow*T2SP + ks*32 + koff);
    #pragma unroll
    for (int t = 0; t < 2; ++t) {
      const int col0 = ch*32 + t*16;
      half8 b = *(const half8*)(w2t + (size_t)(col0 + (lane & 15))*256 + ks*32 + koff);
      acc[t] = __builtin_amdgcn_mfma_f32_16x16x32_f16(a, b, acc[t], 0, 0, 0);
    }
  }
  #pragma unroll
  for (int t = 0; t < 2; ++t) {
    const int col = ch*32 + t*16 + (lane & 15);
    #pragma unroll
    for (int r = 0; r < 4; ++r) {
      const int row = rt*16 + (lane >> 4)*4 + r;
      h2s[row*H2SP + col] = (_Float16)acc[t][r];
    }
  }
  __syncthreads();
  {
    int i = tid;
    int r = i >> 3, c = (i & 7) * 8;
    if (r < vrows) {
      uint4 v = *(const uint4*)(h2s + r*H2SP + c);
      *(uint4*)(h2h + (size_t)(block0 + r)*64 + c) = v;
    }
  }
  const int jj = (lane & 15) * 4;
  const int rg = lane >> 4;
  const int rbase = wv*8 + rg*2;
  const float4 as4 = *(const float4*)(a_src + jj);
  const float4 ad4 = *(const float4*)(a_dst + jj);
  #pragma unroll
  for (int rr = 0; rr < 2; ++rr) {
    int row = block0 + rbase + rr;
    if (row < N) {
      half4 hv = *(const half4*)(h2s + (rbase + rr)*H2SP + jj);
      float ax = (float)hv.x, ay = (float)hv.y, az = (float)hv.z, aw = (float)hv.w;
      float ps = ax*as4.x + ay*as4.y + az*as4.z + aw*as4.w;
      float pd = ax*ad4.x + ay*ad4.y + az*ad4.z + aw*ad4.w;
      #pragma unroll
      for (int o = 8; o; o >>= 1) { ps += __shfl_xor(ps, o); pd += __shfl_xor(pd, o); }
      if ((lane & 15) == 0) { es[row] = ps; ed[row] = pd; }
    }
  }
}

// ------------- graph-1 per-edge weights: w1e[e] = fp16(exp(lrelu(es2[src]+ed2[dst])))
__global__ void k_w1e(const int* __restrict__ csrc, const int* __restrict__ cdst,
                      const float* __restrict__ es, const float* __restrict__ ed,
                      _Float16* __restrict__ w1e, int E) {
  int i = blockIdx.x*blockDim.x + threadIdx.x;
  int stride = gridDim.x*blockDim.x;
  for (; i < E; i += stride) {
    float e = es[csrc[i]] + ed[cdst[i]];
    w1e[i] = (_Float16)__expf(lrelu02(e));
  }
}

// ------------- layer2 aggregation: pure pipelined gather + fdot2 (weights precomputed) ----
__global__ void k_agg2_csr(const int* __restrict__ rowptr, const int* __restrict__ csrc,
                           const _Float16* __restrict__ w1e,
                           const _Float16* __restrict__ h2h, float* __restrict__ out, int N) {
  int tidg = blockIdx.x*blockDim.x + threadIdx.x;
  int wid = tidg >> 6, lane = tidg & 63;
  int nw = (gridDim.x * blockDim.x) >> 6;
  half2v ones; ones.x = (_Float16)1.f; ones.y = (_Float16)1.f;
  for (int d = wid; d < N; d += nw) {
    const int beg = rowptr[d], end = rowptr[d+1];
    float acc = 0.f, wsum = 0.f;
    int k = beg;
    const int kend4 = beg + ((end - beg) & ~3);
    if (k < kend4) {
      int s0 = csrc[k], s1 = csrc[k+1], s2 = csrc[k+2], s3 = csrc[k+3];
      half2v wab, wcd;
      wab.x = w1e[k]; wab.y = w1e[k+1];
      wcd.x = w1e[k+2]; wcd.y = w1e[k+3];
      for (;;) {
        _Float16 x0 = h2h[(size_t)s0*64 + lane];
        _Float16 x1 = h2h[(size_t)s1*64 + lane];
        _Float16 x2 = h2h[(size_t)s2*64 + lane];
        _Float16 x3 = h2h[(size_t)s3*64 + lane];
        k += 4;
        const bool more = (k < kend4);
        int t0 = 0, t1 = 0, t2 = 0, t3 = 0;
        half2v uab, ucd;
        uab.x = uab.y = ucd.x = ucd.y = (_Float16)0.f;
        if (more) {
          t0 = csrc[k]; t1 = csrc[k+1]; t2 = csrc[k+2]; t3 = csrc[k+3];
          uab.x = w1e[k]; uab.y = w1e[k+1];
          ucd.x = w1e[k+2]; ucd.y = w1e[k+3];
        }
        wsum = __builtin_amdgcn_fdot2(wab, ones, wsum, false);
        wsum = __builtin_amdgcn_fdot2(wcd, ones, wsum, false);
        half2v p;
        p.x = x0; p.y = x1;
        acc = __builtin_amdgcn_fdot2(p, wab, acc, false);
        p.x = x2; p.y = x3;
        acc = __builtin_amdgcn_fdot2(p, wcd, acc, false);
        if (!more) break;
        s0 = t0; s1 = t1; s2 = t2; s3 = t3;
        wab = uab; wcd = ucd;
      }
    }
    for (; k < end; ++k) {
      int s = csrc[k];
      float wa = (float)w1e[k];
      wsum += wa;
      acc += wa * (float)h2h[(size_t)s*64 + lane];
    }
    float a = acc / (wsum + 1e-16f);
    float ss = a*a;
    #pragma unroll
    for (int o = 32; o; o >>= 1) ss += __shfl_xor(ss, o);
    float n  = fmaxf(sqrtf(ss), EPSF);
    float sc = tanhf(n) / n;                    // expmap0 scale
    out[(size_t)d*64 + lane] = a * sc;
  }
}

extern "C" void kernel_launch(void* const* d_in, const int* in_sizes, int n_in,
                              void* d_out, int out_size, void* d_ws, size_t ws_size,
                              hipStream_t stream) {
  const float* x      = (const float*)d_in[0];
  const float* W1     = (const float*)d_in[1];
  const float* a_src1 = (const float*)d_in[2];
  const float* a_dst1 = (const float*)d_in[3];
  const float* W2     = (const float*)d_in[4];
  const float* a_src2 = (const float*)d_in[5];
  const float* a_dst2 = (const float*)d_in[6];
  const int*   ei0    = (const int*)d_in[7];
  const int*   ei1    = (const int*)d_in[8];
  const int N  = in_sizes[0] / 128;
  const int E0 = in_sizes[7] / 2;
  const int E1 = in_sizes[8] / 2;
  const int* src0 = ei0;  const int* dst0 = ei0 + E0;
  const int* src1 = ei1;  const int* dst1 = ei1 + E1;
  float* out = (float*)d_out;
  const int nb = (N + 127) >> 7;

  float* ws = (float*)d_ws;
  size_t o = 0;
  float* es1   = ws + o; o += (size_t)N*4;
  float* ed1   = ws + o; o += (size_t)N*4;
  float* es2   = ws + o; o += (size_t)N;
  float* ed2   = ws + o; o += (size_t)N;
  _Float16* lxh = (_Float16*)(ws + o); o += (size_t)N*64;   // N*128 halves
  _Float16* w1t = (_Float16*)(ws + o); o += 16384;          // 32768 halves
  _Float16* w2t = (_Float16*)(ws + o); o += 8192;           // 16384 halves
  _Float16* h1h = (_Float16*)(ws + o); o += (size_t)N*128;  // N*256 halves
  _Float16* t2h = (_Float16*)(ws + o); o += (size_t)N*128;  // N*256 halves
  _Float16* h2h = (_Float16*)(ws + o); o += (size_t)N*32;   // N*64 halves
  o += (o & 1);                                             // 8B align
  half4* w0    = (half4*)(ws + o); o += (size_t)E0*2;       // E0*4 halves
  _Float16* w1e = (_Float16*)(ws + o); o += (size_t)(E1+1)/2; // E1 halves
  u64* temp0 = (u64*)(ws + o); o += (o & 1), o += (size_t)E0*2;
  u64* temp1 = (u64*)(ws + o); o += (size_t)E1*2;
  int* iws = (int*)(ws + o);
  size_t io = 0;
  int* rowptr0 = iws + io; io += N + 1;
  int* rowptr1 = iws + io; io += N + 1;
  int* part0   = iws + io; io += 256*NBMAX;   // partial histograms (written fully)
  int* part1   = iws + io; io += 256*NBMAX;
  int* bbase0  = iws + io; io += NBMAX + 1;
  int* bbase1  = iws + io; io += NBMAX + 1;
  int* bcur0   = iws + io; io += NBMAX;
  int* bcur1   = iws + io; io += NBMAX;
  int* csrc0   = iws + io; io += E0;
  int* csrc1   = iws + io; io += E1;
  int* cdst1   = iws + io; io += E1;

  dim3 blk(256);
  const int blocksA0 = (E0 + 4095) / 4096;
  const int blocksA1 = (E1 + 4095) / 4096;
  const int nblk1 = (N + 31) / 32;
  // merged precompute: w1t, w2t, partial dst-histograms, lx
  k_pre    <<<704 + 2048, blk, 0, stream>>>(W1, W2, x, dst0, E0, dst1, E1,
                                            w1t, w2t, part0, part1, lxh, N);
  // layer-1 GEMM on matrix cores (+ es1/ed1 epilogue) + 2 scan blocks -> bbase/bcur
  k_gemm1_mfma<<<nblk1 + 2, blk, 0, stream>>>(lxh, w1t, a_src1, a_dst1,
                                              h1h, es1, ed1,
                                              part0, part1,
                                              bbase0, bcur0, bbase1, bcur1, nb, N);
  // CSR build (+ graph-0 edge weights, graph-1 cdst fused into bucketB2)
  k_bucketA<<<blocksA0 + blocksA1, blk, 0, stream>>>(
      src0, dst0, bcur0, temp0, E0, blocksA0, src1, dst1, bcur1, temp1, E1, nb);
  k_bucketB2<<<2*nb, blk, 0, stream>>>(temp0, bbase0, rowptr0, csrc0,
                                       es1, ed1, w0,
                                       temp1, bbase1, rowptr1, csrc1, cdst1, N, nb);
  // layer-1 aggregation (pipelined gather, fdot2) + fused maps -> t2h
  k_agg1_csr<<<2048, blk, 0, stream>>>(rowptr0, csrc0, w0, h1h, t2h, N);
  // layer-2 GEMM on matrix cores (+ es2/ed2 epilogue)
  k_gemm2_mfma<<<(N+31)/32, blk, 0, stream>>>(t2h, w2t, a_src2, a_dst2,
                                              h2h, es2, ed2, N);
  // graph-1 per-edge weights, then pure-gather aggregation + fused expmap0
  k_w1e    <<<1024, blk, 0, stream>>>(csrc1, cdst1, es2, ed2, w1e, E1);
  k_agg2_csr<<<2048, blk, 0, stream>>>(rowptr1, csrc1, w1e, h2h, out, N);
}

// Round 29
// 229.527 us; speedup vs baseline: 1.0142x; 1.0142x over previous
//
#include <hip/hip_runtime.h>

#define EPSF 1e-7f
#define NBMAX 512   // max dst-buckets (ceil(N/128)); N=50000 -> 391

typedef __attribute__((ext_vector_type(4))) _Float16 half4;
typedef __attribute__((ext_vector_type(8))) _Float16 half8;
typedef __attribute__((ext_vector_type(2))) _Float16 half2v;
typedef __attribute__((ext_vector_type(4))) float f32x4;
typedef unsigned long long u64;

__device__ __forceinline__ float lrelu02(float x){ return x > 0.f ? x : 0.2f*x; }

// ------- merged precompute: w1t, w2t, partial dst-histograms, lx = logmap0(x) -------
//   blocks 0..127: w1t | 128..191: w2t | 192..703: 2x256 partial hists | 704+: lx
__global__ __launch_bounds__(256) void k_pre(
    const float* __restrict__ W1, const float* __restrict__ W2,
    const float* __restrict__ x,
    const int* __restrict__ dst0, int E0, const int* __restrict__ dst1, int E1,
    _Float16* __restrict__ w1t, _Float16* __restrict__ w2t,
    int* __restrict__ part0, int* __restrict__ part1,
    _Float16* __restrict__ lxh, int N) {
  const int b = blockIdx.x, tid = threadIdx.x;
  if (b < 128) {                       // w1t [256][128] = W1^T fp16
    int idx = b*256 + tid;
    int j = idx >> 7, k = idx & 127;
    w1t[idx] = (_Float16)W1[(size_t)k*256 + j];
    return;
  }
  if (b < 192) {                       // w2t [64][256] = W2^T fp16
    int idx = (b-128)*256 + tid;
    int j = idx >> 8, k = idx & 255;
    w2t[idx] = (_Float16)W2[(size_t)k*64 + j];
    return;
  }
  if (b < 704) {                       // partial histograms (256 blocks per graph)
    const int pb = b - 192;
    const int g = pb >> 8, p = pb & 255;
    const int* dst = g ? dst1 : dst0;
    const int E = g ? E1 : E0;
    int* part = g ? part1 : part0;
    __shared__ int hist[NBMAX];
    for (int i = tid; i < NBMAX; i += 256) hist[i] = 0;
    __syncthreads();
    const int per = (E + 255) >> 8;
    const int lo = p * per, hi = min(lo + per, E);
    for (int i = lo + tid; i < hi; i += 256)
      atomicAdd(&hist[dst[i] >> 7], 1);
    __syncthreads();
    for (int i = tid; i < NBMAX; i += 256) part[p*NBMAX + i] = hist[i];
    return;
  }
  // lx = logmap0(x) fp16: wave per row
  int tidg = (b - 704)*256 + tid;
  int wid = tidg >> 6, lane = tidg & 63;
  int nw = (gridDim.x - 704) * 4;
  for (int row = wid; row < N; row += nw) {
    float2 v = *(const float2*)(x + (size_t)row*128 + lane*2);
    float ss = v.x*v.x + v.y*v.y;
    #pragma unroll
    for (int o = 32; o; o >>= 1) ss += __shfl_xor(ss, o);
    float n  = fmaxf(sqrtf(ss), EPSF);
    float nc = fminf(n, 1.f - 1e-5f);
    float sc = atanhf(nc) / n;                 // logmap0 scale
    half2v hv; hv.x = (_Float16)(v.x*sc); hv.y = (_Float16)(v.y*sc);
    *(half2v*)(lxh + (size_t)row*128 + lane*2) = hv;
  }
}

__global__ __launch_bounds__(256) void k_bucketA(
    const int* __restrict__ src0, const int* __restrict__ dst0,
    int* __restrict__ bcur0, u64* __restrict__ temp0, int E0, int blocksA0,
    const int* __restrict__ src1, const int* __restrict__ dst1,
    int* __restrict__ bcur1, u64* __restrict__ temp1, int E1, int nb) {
  const int g0 = (blockIdx.x < blocksA0);
  const int* src = g0 ? src0 : src1;
  const int* dst = g0 ? dst0 : dst1;
  int* bcur      = g0 ? bcur0 : bcur1;
  u64* temp      = g0 ? temp0 : temp1;
  const int E    = g0 ? E0 : E1;
  const int cb   = g0 ? blockIdx.x : blockIdx.x - blocksA0;
  __shared__ int hist[NBMAX];
  __shared__ int lbase[NBMAX];
  const int tid = threadIdx.x;
  const int chunk0 = cb * 4096;
  const int e_end = min(chunk0 + 4096, E);
  for (int i = tid; i < nb; i += 256) hist[i] = 0;
  __syncthreads();
  for (int i = chunk0 + tid; i < e_end; i += 256)
    atomicAdd(&hist[dst[i] >> 7], 1);
  __syncthreads();
  for (int bn = tid; bn < nb; bn += 256) {
    int c = hist[bn];
    lbase[bn] = c ? atomicAdd(&bcur[bn], c) : 0;
    hist[bn] = 0;
  }
  __syncthreads();
  for (int i = chunk0 + tid; i < e_end; i += 256) {
    int d = dst[i];
    int bn = d >> 7;
    int off = atomicAdd(&hist[bn], 1);
    temp[(size_t)lbase[bn] + off] = ((u64)(unsigned)d << 32) | (unsigned)src[i];
  }
}

// pass B: per bucket, per-dst count + local scan -> rowptr; scatter csrc.
// For graph 0 additionally: per-edge attention weights (fp16).
__global__ __launch_bounds__(256) void k_bucketB2(
    const u64* __restrict__ temp0, const int* __restrict__ bbase0,
    int* __restrict__ rowptr0, int* __restrict__ csrc0,
    const float* __restrict__ es1, const float* __restrict__ ed1,
    half4* __restrict__ w0,
    const u64* __restrict__ temp1, const int* __restrict__ bbase1,
    int* __restrict__ rowptr1, int* __restrict__ csrc1, int N, int nb) {
  const int g0 = (blockIdx.x < nb);
  const u64* temp = g0 ? temp0 : temp1;
  const int* bbase = g0 ? bbase0 : bbase1;
  int* rowptr = g0 ? rowptr0 : rowptr1;
  int* csrc   = g0 ? csrc0 : csrc1;
  const int b = g0 ? blockIdx.x : blockIdx.x - nb;
  __shared__ int lcnt[128];
  __shared__ int lcur[128];
  __shared__ int wt4[4];
  __shared__ float ledv[512];
  const int tid = threadIdx.x;
  const int d0 = b << 7;
  const int d1 = min(d0 + 128, N);
  const int lo = bbase[b], hi = bbase[b+1];
  if (tid < 128) lcnt[tid] = 0;
  if (g0) {
    for (int i = tid; i < (d1 - d0)*4; i += 256) ledv[i] = ed1[d0*4 + i];
  }
  __syncthreads();
  for (int k = lo + tid; k < hi; k += 256)
    atomicAdd(&lcnt[(int)(temp[k] >> 32) - d0], 1);
  __syncthreads();
  int v = (tid < 128) ? lcnt[tid] : 0;
  const int lane = tid & 63, w = tid >> 6;
  int inc = v;
  #pragma unroll
  for (int o = 1; o < 64; o <<= 1) { int t = __shfl_up(inc, o); if (lane >= o) inc += t; }
  if (lane == 63) wt4[w] = inc;
  __syncthreads();
  int woff = 0;
  for (int i = 0; i < w; ++i) woff += wt4[i];
  int excl = lo + woff + inc - v;
  if (tid < d1 - d0) { rowptr[d0 + tid] = excl; lcur[tid] = excl; }
  if (b == nb-1 && tid == 0) rowptr[N] = hi;
  __syncthreads();
  for (int k = lo + tid; k < hi; k += 256) {
    u64 p = temp[k];
    int d = (int)(p >> 32);
    int s = (int)(unsigned)p;
    int pos = atomicAdd(&lcur[d - d0], 1);
    csrc[pos] = s;
    if (g0) {
      float4 e = *(const float4*)(es1 + (size_t)s*4);
      int ld = (d - d0)*4;
      half4 wh;
      wh.x = (_Float16)__expf(lrelu02(e.x + ledv[ld+0]));
      wh.y = (_Float16)__expf(lrelu02(e.y + ledv[ld+1]));
      wh.z = (_Float16)__expf(lrelu02(e.z + ledv[ld+2]));
      wh.w = (_Float16)__expf(lrelu02(e.w + ledv[ld+3]));
      w0[pos] = wh;
    }
  }
}

// ------------- gemm1 via MFMA: h1 = lx @ W1 (fp16 in, f32 acc, fp16 out)
//   + epilogue: es1/ed1 [N,4] from the h1 LDS tile
//   + 2 appended blocks: bucket-count scan (sums k_pre partials) -> bbase/bcur
#define LXP 136   // padded halves per lx row in LDS
#define H1P 264   // padded halves per h1 row in LDS
__global__ __launch_bounds__(256) void k_gemm1_mfma(
    const _Float16* __restrict__ lxh, const _Float16* __restrict__ w1t,
    const float* __restrict__ a_src, const float* __restrict__ a_dst,
    _Float16* __restrict__ h1h, float* __restrict__ es, float* __restrict__ ed,
    const int* __restrict__ part0, const int* __restrict__ part1,
    int* __restrict__ bbase0, int* __restrict__ bcur0,
    int* __restrict__ bbase1, int* __restrict__ bcur1, int nb, int N) {
  __shared__ _Float16 lxs[32*LXP];   // ~8.5 KB
  __shared__ _Float16 h1s[32*H1P];   // ~16.5 KB
  __shared__ int swt[4];
  const int tid = threadIdx.x;
  const int nblk = (N + 31) >> 5;
  if ((int)blockIdx.x >= nblk) {
    // ---- bucket scan for graph g (replaces k_bscan) ----
    const int g = (int)blockIdx.x - nblk;
    const int* part = g ? part1 : part0;
    int* bbase = g ? bbase1 : bbase0;
    int* bcur  = g ? bcur1  : bcur0;
    const int i0 = tid*2, i1 = tid*2 + 1;
    int v0 = 0, v1 = 0;
    for (int p = 0; p < 256; ++p) {
      v0 += part[p*NBMAX + i0];
      v1 += part[p*NBMAX + i1];
    }
    int s = v0 + v1;
    const int lane = tid & 63, w = tid >> 6;
    int inc = s;
    #pragma unroll
    for (int o = 1; o < 64; o <<= 1) { int t = __shfl_up(inc, o); if (lane >= o) inc += t; }
    if (lane == 63) swt[w] = inc;
    __syncthreads();
    int woff = 0;
    for (int i = 0; i < w; ++i) woff += swt[i];
    int excl = woff + inc - s;
    if (i0 < nb) { bbase[i0] = excl; bcur[i0] = excl; }
    if (i1 < nb) { bbase[i1] = excl + v0; bcur[i1] = excl + v0; }
    if (tid == 255) bbase[nb] = excl + s;   // beyond-nb partials are zero
    return;
  }
  const int block0 = blockIdx.x * 32;
  const int vrows = min(32, N - block0);
  for (int i = tid; i < 512; i += 256) {
    int r = i >> 4, c = (i & 15) * 8;
    uint4 v = make_uint4(0u,0u,0u,0u);
    if (r < vrows) v = *(const uint4*)(lxh + (size_t)(block0 + r)*128 + c);
    *(uint4*)(lxs + r*LXP + c) = v;
  }
  __syncthreads();
  const int wv = tid >> 6, lane = tid & 63;
  const int rt = wv & 1;               // row-tile (16 rows)
  const int ch = wv >> 1;              // col-half (128 cols)
  const int arow = rt*16 + (lane & 15);
  const int koff = (lane >> 4) * 8;
  f32x4 acc[8];
  #pragma unroll
  for (int t = 0; t < 8; ++t) acc[t] = (f32x4){0.f,0.f,0.f,0.f};
  #pragma unroll
  for (int ks = 0; ks < 4; ++ks) {
    half8 a = *(const half8*)(lxs + arow*LXP + ks*32 + koff);
    #pragma unroll
    for (int t = 0; t < 8; ++t) {
      const int col0 = ch*128 + t*16;
      half8 b = *(const half8*)(w1t + (size_t)(col0 + (lane & 15))*128 + ks*32 + koff);
      acc[t] = __builtin_amdgcn_mfma_f32_16x16x32_f16(a, b, acc[t], 0, 0, 0);
    }
  }
  #pragma unroll
  for (int t = 0; t < 8; ++t) {
    const int col = ch*128 + t*16 + (lane & 15);
    #pragma unroll
    for (int r = 0; r < 4; ++r) {
      const int row = rt*16 + (lane >> 4)*4 + r;
      h1s[row*H1P + col] = (_Float16)acc[t][r];
    }
  }
  __syncthreads();
  for (int i = tid; i < 1024; i += 256) {
    int r = i >> 5, c = (i & 31) * 8;
    if (r < vrows) {
      uint4 v = *(const uint4*)(h1s + r*H1P + c);
      *(uint4*)(h1h + (size_t)(block0 + r)*256 + c) = v;
    }
  }
  // epilogue: es/ed per (row, head) from h1s; lane owns cols lane*4..+3
  const int head = lane >> 4;
  const float4 as4 = *(const float4*)(a_src + lane*4);
  const float4 ad4 = *(const float4*)(a_dst + lane*4);
  #pragma unroll
  for (int r8 = 0; r8 < 8; ++r8) {
    int rl = wv*8 + r8;
    int row = block0 + rl;
    if (row >= N) break;
    half4 hv = *(const half4*)(h1s + rl*H1P + lane*4);
    float ax = (float)hv.x, ay = (float)hv.y, az = (float)hv.z, aw = (float)hv.w;
    float ps = ax*as4.x + ay*as4.y + az*as4.z + aw*as4.w;
    float pd = ax*ad4.x + ay*ad4.y + az*ad4.z + aw*ad4.w;
    #pragma unroll
    for (int o = 8; o; o >>= 1) { ps += __shfl_xor(ps, o); pd += __shfl_xor(pd, o); }
    if ((lane & 15) == 0) { es[row*4 + head] = ps; ed[row*4 + head] = pd; }
  }
}

// ------------- layer1 aggregation: pipelined gather + packed fdot2 accumulation -----------
__global__ void k_agg1_csr(const int* __restrict__ rowptr, const int* __restrict__ csrc,
                           const half4* __restrict__ w0,
                           const _Float16* __restrict__ h1h, _Float16* __restrict__ t2h,
                           int N) {
  int tidg = blockIdx.x*blockDim.x + threadIdx.x;
  int wid = tidg >> 6, lane = tidg & 63;
  int nw = (gridDim.x * blockDim.x) >> 6;
  const int h = lane >> 4;
  const _Float16* wp = (const _Float16*)w0;
  half2v ones; ones.x = (_Float16)1.f; ones.y = (_Float16)1.f;
  for (int d = wid; d < N; d += nw) {
    const int beg = rowptr[d], end = rowptr[d+1];
    float4 acc = make_float4(0.f,0.f,0.f,0.f);
    float wsum = 0.f;
    int k = beg;
    const int kend4 = beg + ((end - beg) & ~3);
    if (k < kend4) {
      int s0 = csrc[k], s1 = csrc[k+1], s2 = csrc[k+2], s3 = csrc[k+3];
      half2v wab, wcd;
      wab.x = wp[(size_t)(k+0)*4 + h]; wab.y = wp[(size_t)(k+1)*4 + h];
      wcd.x = wp[(size_t)(k+2)*4 + h]; wcd.y = wp[(size_t)(k+3)*4 + h];
      for (;;) {
        half4 v0 = *(const half4*)(h1h + (size_t)s0*256 + lane*4);
        half4 v1 = *(const half4*)(h1h + (size_t)s1*256 + lane*4);
        half4 v2 = *(const half4*)(h1h + (size_t)s2*256 + lane*4);
        half4 v3 = *(const half4*)(h1h + (size_t)s3*256 + lane*4);
        k += 4;
        const bool more = (k < kend4);
        int t0 = 0, t1 = 0, t2 = 0, t3 = 0;
        half2v uab, ucd;
        uab.x = uab.y = ucd.x = ucd.y = (_Float16)0.f;
        if (more) {
          t0 = csrc[k]; t1 = csrc[k+1]; t2 = csrc[k+2]; t3 = csrc[k+3];
          uab.x = wp[(size_t)(k+0)*4 + h]; uab.y = wp[(size_t)(k+1)*4 + h];
          ucd.x = wp[(size_t)(k+2)*4 + h]; ucd.y = wp[(size_t)(k+3)*4 + h];
        }
        wsum = __builtin_amdgcn_fdot2(wab, ones, wsum, false);
        wsum = __builtin_amdgcn_fdot2(wcd, ones, wsum, false);
        half2v p;
        p.x = v0.x; p.y = v1.x;
        acc.x = __builtin_amdgcn_fdot2(p, wab, acc.x, false);
        p.x = v2.x; p.y = v3.x;
        acc.x = __builtin_amdgcn_fdot2(p, wcd, acc.x, false);
        p.x = v0.y; p.y = v1.y;
        acc.y = __builtin_amdgcn_fdot2(p, wab, acc.y, false);
        p.x = v2.y; p.y = v3.y;
        acc.y = __builtin_amdgcn_fdot2(p, wcd, acc.y, false);
        p.x = v0.z; p.y = v1.z;
        acc.z = __builtin_amdgcn_fdot2(p, wab, acc.z, false);
        p.x = v2.z; p.y = v3.z;
        acc.z = __builtin_amdgcn_fdot2(p, wcd, acc.z, false);
        p.x = v0.w; p.y = v1.w;
        acc.w = __builtin_amdgcn_fdot2(p, wab, acc.w, false);
        p.x = v2.w; p.y = v3.w;
        acc.w = __builtin_amdgcn_fdot2(p, wcd, acc.w, false);
        if (!more) break;
        s0 = t0; s1 = t1; s2 = t2; s3 = t3;
        wab = uab; wcd = ucd;
      }
    }
    for (; k < end; ++k) {
      int s = csrc[k];
      float wa = (float)wp[(size_t)k*4 + h];
      half4 hv = *(const half4*)(h1h + (size_t)s*256 + lane*4);
      wsum += wa;
      acc.x += wa*(float)hv.x; acc.y += wa*(float)hv.y;
      acc.z += wa*(float)hv.z; acc.w += wa*(float)hv.w;
    }
    float inv = 1.f / (wsum + 1e-16f);
    float ax = acc.x*inv, ay = acc.y*inv, az = acc.z*inv, aw = acc.w*inv;
    float ss = ax*ax + ay*ay + az*az + aw*aw;
    #pragma unroll
    for (int o = 32; o; o >>= 1) ss += __shfl_xor(ss, o);
    float n  = fmaxf(sqrtf(ss), EPSF);
    float s1 = tanhf(n) / n;                    // expmap0 scale
    float n2 = fmaxf(s1 * n, EPSF);             // = tanh(n), clamped
    float nc = fminf(n2, 1.f - 1e-5f);
    float sc = s1 * atanhf(nc) / n2;
    half4 o4; o4.x = (_Float16)(ax*sc); o4.y = (_Float16)(ay*sc);
              o4.z = (_Float16)(az*sc); o4.w = (_Float16)(aw*sc);
    *(half4*)(t2h + (size_t)d*256 + lane*4) = o4;
  }
}

// ------------- gemm2 via MFMA: h2 = t2 @ W2 (fp16 in, f32 acc); es2/ed2 epilogue
#define T2SP 264  // padded halves per t2 row in LDS
#define H2SP 72   // padded halves per h2 row in LDS
__global__ __launch_bounds__(256) void k_gemm2_mfma(
    const _Float16* __restrict__ t2h, const _Float16* __restrict__ w2t,
    const float* __restrict__ a_src, const float* __restrict__ a_dst,
    _Float16* __restrict__ h2h, float* __restrict__ es, float* __restrict__ ed, int N) {
  __shared__ _Float16 t2s[32*T2SP];  // ~16.9 KB
  __shared__ _Float16 h2s[32*H2SP];  // ~4.6 KB
  const int tid = threadIdx.x;
  const int block0 = blockIdx.x * 32;
  const int vrows = min(32, N - block0);
  for (int i = tid; i < 1024; i += 256) {
    int r = i >> 5, c = (i & 31) * 8;
    uint4 v = make_uint4(0u,0u,0u,0u);
    if (r < vrows) v = *(const uint4*)(t2h + (size_t)(block0 + r)*256 + c);
    *(uint4*)(t2s + r*T2SP + c) = v;
  }
  __syncthreads();
  const int wv = tid >> 6, lane = tid & 63;
  const int rt = wv & 1;
  const int ch = wv >> 1;
  const int arow = rt*16 + (lane & 15);
  const int koff = (lane >> 4) * 8;
  f32x4 acc[2];
  acc[0] = (f32x4){0.f,0.f,0.f,0.f};
  acc[1] = (f32x4){0.f,0.f,0.f,0.f};
  #pragma unroll
  for (int ks = 0; ks < 8; ++ks) {
    half8 a = *(const half8*)(t2s + arow*T2SP + ks*32 + koff);
    #pragma unroll
    for (int t = 0; t < 2; ++t) {
      const int col0 = ch*32 + t*16;
      half8 b = *(const half8*)(w2t + (size_t)(col0 + (lane & 15))*256 + ks*32 + koff);
      acc[t] = __builtin_amdgcn_mfma_f32_16x16x32_f16(a, b, acc[t], 0, 0, 0);
    }
  }
  #pragma unroll
  for (int t = 0; t < 2; ++t) {
    const int col = ch*32 + t*16 + (lane & 15);
    #pragma unroll
    for (int r = 0; r < 4; ++r) {
      const int row = rt*16 + (lane >> 4)*4 + r;
      h2s[row*H2SP + col] = (_Float16)acc[t][r];
    }
  }
  __syncthreads();
  {
    int i = tid;
    int r = i >> 3, c = (i & 7) * 8;
    if (r < vrows) {
      uint4 v = *(const uint4*)(h2s + r*H2SP + c);
      *(uint4*)(h2h + (size_t)(block0 + r)*64 + c) = v;
    }
  }
  const int jj = (lane & 15) * 4;
  const int rg = lane >> 4;
  const int rbase = wv*8 + rg*2;
  const float4 as4 = *(const float4*)(a_src + jj);
  const float4 ad4 = *(const float4*)(a_dst + jj);
  #pragma unroll
  for (int rr = 0; rr < 2; ++rr) {
    int row = block0 + rbase + rr;
    if (row < N) {
      half4 hv = *(const half4*)(h2s + (rbase + rr)*H2SP + jj);
      float ax = (float)hv.x, ay = (float)hv.y, az = (float)hv.z, aw = (float)hv.w;
      float ps = ax*as4.x + ay*as4.y + az*as4.z + aw*as4.w;
      float pd = ax*ad4.x + ay*ad4.y + az*ad4.z + aw*ad4.w;
      #pragma unroll
      for (int o = 8; o; o >>= 1) { ps += __shfl_xor(ps, o); pd += __shfl_xor(pd, o); }
      if ((lane & 15) == 0) { es[row] = ps; ed[row] = pd; }
    }
  }
}

// ------------- layer2 aggregation (CSR, wave per dst, pipelined) + fused expmap0 ---------
__global__ void k_agg2_csr(const int* __restrict__ rowptr, const int* __restrict__ csrc,
                           const float* __restrict__ es, const float* __restrict__ ed,
                           const _Float16* __restrict__ h2h, float* __restrict__ out, int N) {
  int tidg = blockIdx.x*blockDim.x + threadIdx.x;
  int wid = tidg >> 6, lane = tidg & 63;
  int nw = (gridDim.x * blockDim.x) >> 6;
  for (int d = wid; d < N; d += nw) {
    const int beg = rowptr[d], end = rowptr[d+1];
    const float edv = ed[d];
    float acc = 0.f, wsum = 0.f;
    int k = beg;
    const int kend4 = beg + ((end - beg) & ~3);
    if (k < kend4) {
      int s0 = csrc[k], s1 = csrc[k+1], s2 = csrc[k+2], s3 = csrc[k+3];
      for (;;) {
        float e0 = es[s0], e1 = es[s1], e2 = es[s2], e3 = es[s3];
        float x0 = (float)h2h[(size_t)s0*64 + lane];
        float x1 = (float)h2h[(size_t)s1*64 + lane];
        float x2 = (float)h2h[(size_t)s2*64 + lane];
        float x3 = (float)h2h[(size_t)s3*64 + lane];
        k += 4;
        const bool more = (k < kend4);
        int t0 = 0, t1 = 0, t2 = 0, t3 = 0;
        if (more) { t0 = csrc[k]; t1 = csrc[k+1]; t2 = csrc[k+2]; t3 = csrc[k+3]; }
        float w0 = __expf(lrelu02(e0 + edv));
        float w1 = __expf(lrelu02(e1 + edv));
        float w2 = __expf(lrelu02(e2 + edv));
        float w3 = __expf(lrelu02(e3 + edv));
        wsum += (w0 + w1) + (w2 + w3);
        acc += w0*x0 + w1*x1 + w2*x2 + w3*x3;
        if (!more) break;
        s0 = t0; s1 = t1; s2 = t2; s3 = t3;
      }
    }
    for (; k < end; ++k) {
      int s = csrc[k];
      float w = __expf(lrelu02(es[s] + edv));
      wsum += w;
      acc += w * (float)h2h[(size_t)s*64 + lane];
    }
    float a = acc / (wsum + 1e-16f);
    float ss = a*a;
    #pragma unroll
    for (int o = 32; o; o >>= 1) ss += __shfl_xor(ss, o);
    float n  = fmaxf(sqrtf(ss), EPSF);
    float sc = tanhf(n) / n;                    // expmap0 scale
    out[(size_t)d*64 + lane] = a * sc;
  }
}

extern "C" void kernel_launch(void* const* d_in, const int* in_sizes, int n_in,
                              void* d_out, int out_size, void* d_ws, size_t ws_size,
                              hipStream_t stream) {
  const float* x      = (const float*)d_in[0];
  const float* W1     = (const float*)d_in[1];
  const float* a_src1 = (const float*)d_in[2];
  const float* a_dst1 = (const float*)d_in[3];
  const float* W2     = (const float*)d_in[4];
  const float* a_src2 = (const float*)d_in[5];
  const float* a_dst2 = (const float*)d_in[6];
  const int*   ei0    = (const int*)d_in[7];
  const int*   ei1    = (const int*)d_in[8];
  const int N  = in_sizes[0] / 128;
  const int E0 = in_sizes[7] / 2;
  const int E1 = in_sizes[8] / 2;
  const int* src0 = ei0;  const int* dst0 = ei0 + E0;
  const int* src1 = ei1;  const int* dst1 = ei1 + E1;
  float* out = (float*)d_out;
  const int nb = (N + 127) >> 7;

  float* ws = (float*)d_ws;
  size_t o = 0;
  float* es1   = ws + o; o += (size_t)N*4;
  float* ed1   = ws + o; o += (size_t)N*4;
  float* es2   = ws + o; o += (size_t)N;
  float* ed2   = ws + o; o += (size_t)N;
  _Float16* lxh = (_Float16*)(ws + o); o += (size_t)N*64;   // N*128 halves
  _Float16* w1t = (_Float16*)(ws + o); o += 16384;          // 32768 halves
  _Float16* w2t = (_Float16*)(ws + o); o += 8192;           // 16384 halves
  _Float16* h1h = (_Float16*)(ws + o); o += (size_t)N*128;  // N*256 halves
  _Float16* t2h = (_Float16*)(ws + o); o += (size_t)N*128;  // N*256 halves
  _Float16* h2h = (_Float16*)(ws + o); o += (size_t)N*32;   // N*64 halves
  o += (o & 1);                                             // 8B align
  half4* w0    = (half4*)(ws + o); o += (size_t)E0*2;       // E0*4 halves
  u64* temp0 = (u64*)(ws + o); o += (size_t)E0*2;
  u64* temp1 = (u64*)(ws + o); o += (size_t)E1*2;
  int* iws = (int*)(ws + o);
  size_t io = 0;
  int* rowptr0 = iws + io; io += N + 1;
  int* rowptr1 = iws + io; io += N + 1;
  int* part0   = iws + io; io += 256*NBMAX;   // partial histograms (written fully)
  int* part1   = iws + io; io += 256*NBMAX;
  int* bbase0  = iws + io; io += NBMAX + 1;
  int* bbase1  = iws + io; io += NBMAX + 1;
  int* bcur0   = iws + io; io += NBMAX;
  int* bcur1   = iws + io; io += NBMAX;
  int* csrc0   = iws + io; io += E0;
  int* csrc1   = iws + io; io += E1;

  dim3 blk(256);
  const int blocksA0 = (E0 + 4095) / 4096;
  const int blocksA1 = (E1 + 4095) / 4096;
  const int nblk1 = (N + 31) / 32;
  // merged precompute: w1t, w2t, partial dst-histograms, lx
  k_pre    <<<704 + 2048, blk, 0, stream>>>(W1, W2, x, dst0, E0, dst1, E1,
                                            w1t, w2t, part0, part1, lxh, N);
  // layer-1 GEMM on matrix cores (+ es1/ed1 epilogue) + 2 scan blocks -> bbase/bcur
  k_gemm1_mfma<<<nblk1 + 2, blk, 0, stream>>>(lxh, w1t, a_src1, a_dst1,
                                              h1h, es1, ed1,
                                              part0, part1,
                                              bbase0, bcur0, bbase1, bcur1, nb, N);
  // CSR build (+ graph-0 edge weights fused into bucketB2)
  k_bucketA<<<blocksA0 + blocksA1, blk, 0, stream>>>(
      src0, dst0, bcur0, temp0, E0, blocksA0, src1, dst1, bcur1, temp1, E1, nb);
  k_bucketB2<<<2*nb, blk, 0, stream>>>(temp0, bbase0, rowptr0, csrc0,
                                       es1, ed1, w0,
                                       temp1, bbase1, rowptr1, csrc1, N, nb);
  // layer-1 aggregation (pipelined gather, fdot2) + fused maps -> t2h
  k_agg1_csr<<<2048, blk, 0, stream>>>(rowptr0, csrc0, w0, h1h, t2h, N);
  // layer-2 GEMM on matrix cores (+ es2/ed2 epilogue)
  k_gemm2_mfma<<<(N+31)/32, blk, 0, stream>>>(t2h, w2t, a_src2, a_dst2,
                                              h2h, es2, ed2, N);
  k_agg2_csr<<<2048, blk, 0, stream>>>(rowptr1, csrc1, es2, ed2, h2h, out, N);
}